// Round 1
// baseline (153.103 us; speedup 1.0000x reference)
//
#include <hip/hip_runtime.h>
#include <math.h>

#define NP 10          // num prototypes
#define NQ 10          // queue length
#define NB 8           // batch
#define TEMP_INV (1.0f/0.07f)
#define DHW (64*128*128)   // 1,048,576 voxels per sample

// ---------------------------------------------------------------------------
// Kernel 1: per-voxel argmax over 10 prototypes -> per-sample histogram.
// x layout: [B, C=2, D, H, W]; channel 0 and 1 are DHW apart.
// Each thread keeps a 10-entry register histogram (predicated adds, no
// dynamic indexing -> stays in VGPRs), reduced via shared then global atomics.
// ---------------------------------------------------------------------------
__global__ __launch_bounds__(256) void hist_kernel(const float* __restrict__ x,
                                                   const float* __restrict__ protos,
                                                   unsigned int* __restrict__ counts) {
    const int b   = blockIdx.y;
    const int tid = threadIdx.x;

    // prototype coefficients (uniform-address loads, L1-cached broadcast)
    float p0[NP], p1[NP];
#pragma unroll
    for (int p = 0; p < NP; ++p) {
        p0[p] = protos[p * 2 + 0];
        p1[p] = protos[p * 2 + 1];
    }

    const float4* x0 = (const float4*)(x + (size_t)b * 2 * DHW);
    const float4* x1 = (const float4*)(x + (size_t)b * 2 * DHW + DHW);

    unsigned int cnt[NP];
#pragma unroll
    for (int p = 0; p < NP; ++p) cnt[p] = 0u;

    const int n4      = DHW / 4;                        // 262,144 float4s
    const int stride  = gridDim.x * blockDim.x;         // threads per sample
    for (int i = blockIdx.x * blockDim.x + tid; i < n4; i += stride) {
        float4 a = x0[i];
        float4 c = x1[i];
        float xa[4] = {a.x, a.y, a.z, a.w};
        float xc[4] = {c.x, c.y, c.z, c.w};
#pragma unroll
        for (int j = 0; j < 4; ++j) {
            float best = -INFINITY;
            int   bi   = 0;
#pragma unroll
            for (int p = 0; p < NP; ++p) {
                float sim = xa[j] * p0[p] + xc[j] * p1[p];
                if (sim > best) { best = sim; bi = p; }   // strict > == np.argmax first-max
            }
#pragma unroll
            for (int p = 0; p < NP; ++p) cnt[p] += (bi == p) ? 1u : 0u;
        }
    }

    __shared__ unsigned int smem[NP];
    if (tid < NP) smem[tid] = 0u;
    __syncthreads();
#pragma unroll
    for (int p = 0; p < NP; ++p) atomicAdd(&smem[p], cnt[p]);
    __syncthreads();
    if (tid < NP) atomicAdd(&counts[b * NP + tid], smem[tid]);
}

// ---------------------------------------------------------------------------
// Kernel 2: tiny finalize. pool = counts @ protos, normalize, contrastive loss.
// One block; threads 0..7 each handle one sample.
// ---------------------------------------------------------------------------
__global__ void finalize_kernel(const unsigned int* __restrict__ counts,
                                const float* __restrict__ protos,
                                const float* __restrict__ queue0,
                                const float* __restrict__ queue1,
                                float* __restrict__ out) {
    __shared__ float partial[NB];
    const int t = threadIdx.x;
    if (t < NB) {
        float pool0 = 0.f, pool1 = 0.f;
#pragma unroll
        for (int p = 0; p < NP; ++p) {
            float c = (float)counts[t * NP + p];
            pool0 += c * protos[p * 2 + 0];
            pool1 += c * protos[p * 2 + 1];
        }
        float n = fmaxf(sqrtf(pool0 * pool0 + pool1 * pool1), 1e-12f);
        float pn0 = pool0 / n, pn1 = pool1 / n;

        float ln[NQ];
        float maxlog = -INFINITY;
#pragma unroll
        for (int q = 0; q < NQ; ++q) {
            float f0 = queue0[q * 2], f1 = queue0[q * 2 + 1];
            float nn = fmaxf(sqrtf(f0 * f0 + f1 * f1), 1e-12f);
            float l  = (pn0 * f0 + pn1 * f1) / nn * TEMP_INV;
            ln[q] = l;
            maxlog = fmaxf(maxlog, l);
        }
        float lneg = 0.f;
#pragma unroll
        for (int q = 0; q < NQ; ++q) lneg += expf(ln[q] - maxlog);

        float lsum = 0.f;
#pragma unroll
        for (int q = 0; q < NQ; ++q) {
            float f0 = queue1[q * 2], f1 = queue1[q * 2 + 1];
            float nn = fmaxf(sqrtf(f0 * f0 + f1 * f1), 1e-12f);
            float lp = (pn0 * f0 + pn1 * f1) / nn * TEMP_INV - maxlog;
            float v  = fmaxf(lneg + expf(lp), 1e-4f);
            lsum += -(lp - logf(v));
        }
        partial[t] = lsum / (float)NQ;
    }
    __syncthreads();
    if (t == 0) {
        float s = 0.f;
#pragma unroll
        for (int i = 0; i < NB; ++i) s += partial[i];
        out[0] = s / (float)NB;
    }
}

extern "C" void kernel_launch(void* const* d_in, const int* in_sizes, int n_in,
                              void* d_out, int out_size, void* d_ws, size_t ws_size,
                              hipStream_t stream) {
    const float* x      = (const float*)d_in[0];
    // d_in[1] = label — mathematically cancels out of the loss; never read.
    const float* protos = (const float*)d_in[2];
    const float* q0     = (const float*)d_in[3];
    const float* q1     = (const float*)d_in[4];
    float* out          = (float*)d_out;

    unsigned int* counts = (unsigned int*)d_ws;   // [8][10] uint32, 320 B

    // d_ws is re-poisoned to 0xAA before every call — zero it (capturable).
    hipMemsetAsync(counts, 0, NB * NP * sizeof(unsigned int), stream);

    dim3 grid(128, NB);   // 1024 blocks total, 8 float4-iterations per thread
    hist_kernel<<<grid, 256, 0, stream>>>(x, protos, counts);
    finalize_kernel<<<1, 64, 0, stream>>>(counts, protos, q0, q1, out);
}

// Round 2
// 143.924 us; speedup vs baseline: 1.0638x; 1.0638x over previous
//
#include <hip/hip_runtime.h>
#include <math.h>

#define NP 10          // num prototypes
#define NQ 10          // queue length
#define NB 8           // batch
#define TEMP_INV (1.0f/0.07f)
#define DHW (64*128*128)       // 1,048,576 voxels per sample
#define BLOCKS_X 128           // blocks per sample
#define THREADS 256
#define K_ITERS 8              // float4-pairs per thread: 128*256*8*4 == DHW
#define STRIDE4 (BLOCKS_X*THREADS)   // 32768 float4s

// ---------------------------------------------------------------------------
// Kernel 1: per-voxel argmax over 10 prototypes -> per-block partial histogram.
// No atomics anywhere: per-thread u64 packed histogram (6-bit fields, max 32
// per field), wave shuffle-reduce, per-wave LDS slots, per-block global store.
// ---------------------------------------------------------------------------
__global__ __launch_bounds__(THREADS) void hist_kernel(const float* __restrict__ x,
                                                       const float* __restrict__ protos,
                                                       unsigned int* __restrict__ partial) {
    const int b    = blockIdx.y;
    const int tid  = threadIdx.x;
    const int lane = tid & 63;
    const int wave = tid >> 6;

    float p0[NP], p1[NP];
#pragma unroll
    for (int p = 0; p < NP; ++p) {
        p0[p] = protos[p * 2 + 0];
        p1[p] = protos[p * 2 + 1];
    }

    const float4* x0 = (const float4*)(x + (size_t)b * 2 * DHW);
    const float4* x1 = (const float4*)(x + (size_t)b * 2 * DHW + DHW);
    const int i0 = blockIdx.x * THREADS + tid;

    unsigned long long packed = 0ull;   // 10 x 6-bit counters

#pragma unroll
    for (int k = 0; k < K_ITERS; ++k) {
        float4 a = x0[i0 + k * STRIDE4];
        float4 c = x1[i0 + k * STRIDE4];
        float xa[4] = {a.x, a.y, a.z, a.w};
        float xc[4] = {c.x, c.y, c.z, c.w};
#pragma unroll
        for (int j = 0; j < 4; ++j) {
            float best = xa[j] * p0[0] + xc[j] * p1[0];
            int   bi   = 0;
#pragma unroll
            for (int p = 1; p < NP; ++p) {
                float sim = xa[j] * p0[p] + xc[j] * p1[p];
                if (sim > best) { best = sim; bi = p; }   // strict > == np.argmax first-max
            }
            packed += 1ull << (6 * bi);
        }
    }

    // wave-level reduction of each 6-bit field, then per-wave LDS slot
    __shared__ unsigned int smem[THREADS / 64][NP];
#pragma unroll
    for (int p = 0; p < NP; ++p) {
        unsigned int c = (unsigned int)((packed >> (6 * p)) & 63ull);
#pragma unroll
        for (int off = 32; off > 0; off >>= 1)
            c += __shfl_xor(c, off, 64);
        if (lane == 0) smem[wave][p] = c;
    }
    __syncthreads();

    if (tid < NP) {
        unsigned int t = smem[0][tid] + smem[1][tid] + smem[2][tid] + smem[3][tid];
        partial[((size_t)b * BLOCKS_X + blockIdx.x) * NP + tid] = t;   // plain store
    }
}

// ---------------------------------------------------------------------------
// Kernel 2: sum partials -> counts; pool = counts @ protos; contrastive loss.
// ---------------------------------------------------------------------------
__global__ void finalize_kernel(const unsigned int* __restrict__ partial,
                                const float* __restrict__ protos,
                                const float* __restrict__ queue0,
                                const float* __restrict__ queue1,
                                float* __restrict__ out) {
    __shared__ float scount[NB][NP];
    __shared__ float ploss[NB];
    const int t = threadIdx.x;

    if (t < NB * NP) {
        const int b = t / NP, p = t % NP;
        unsigned int s = 0;
#pragma unroll 8
        for (int j = 0; j < BLOCKS_X; ++j)
            s += partial[((size_t)b * BLOCKS_X + j) * NP + p];
        scount[b][p] = (float)s;
    }
    __syncthreads();

    if (t < NB) {
        float pool0 = 0.f, pool1 = 0.f;
#pragma unroll
        for (int p = 0; p < NP; ++p) {
            pool0 += scount[t][p] * protos[p * 2 + 0];
            pool1 += scount[t][p] * protos[p * 2 + 1];
        }
        float n = fmaxf(sqrtf(pool0 * pool0 + pool1 * pool1), 1e-12f);
        float pn0 = pool0 / n, pn1 = pool1 / n;

        float ln[NQ];
        float maxlog = -INFINITY;
#pragma unroll
        for (int q = 0; q < NQ; ++q) {
            float f0 = queue0[q * 2], f1 = queue0[q * 2 + 1];
            float nn = fmaxf(sqrtf(f0 * f0 + f1 * f1), 1e-12f);
            float l  = (pn0 * f0 + pn1 * f1) / nn * TEMP_INV;
            ln[q] = l;
            maxlog = fmaxf(maxlog, l);
        }
        float lneg = 0.f;
#pragma unroll
        for (int q = 0; q < NQ; ++q) lneg += expf(ln[q] - maxlog);

        float lsum = 0.f;
#pragma unroll
        for (int q = 0; q < NQ; ++q) {
            float f0 = queue1[q * 2], f1 = queue1[q * 2 + 1];
            float nn = fmaxf(sqrtf(f0 * f0 + f1 * f1), 1e-12f);
            float lp = (pn0 * f0 + pn1 * f1) / nn * TEMP_INV - maxlog;
            float v  = fmaxf(lneg + expf(lp), 1e-4f);
            lsum += -(lp - logf(v));
        }
        ploss[t] = lsum / (float)NQ;
    }
    __syncthreads();
    if (t == 0) {
        float s = 0.f;
#pragma unroll
        for (int i = 0; i < NB; ++i) s += ploss[i];
        out[0] = s / (float)NB;
    }
}

extern "C" void kernel_launch(void* const* d_in, const int* in_sizes, int n_in,
                              void* d_out, int out_size, void* d_ws, size_t ws_size,
                              hipStream_t stream) {
    const float* x      = (const float*)d_in[0];
    // d_in[1] = label — cancels out of the loss exactly; never read.
    const float* protos = (const float*)d_in[2];
    const float* q0     = (const float*)d_in[3];
    const float* q1     = (const float*)d_in[4];
    float* out          = (float*)d_out;

    unsigned int* partial = (unsigned int*)d_ws;   // [8*128][10] u32 = 40 KB
    // No memset needed: every block unconditionally writes its partial row.

    dim3 grid(BLOCKS_X, NB);
    hist_kernel<<<grid, THREADS, 0, stream>>>(x, protos, partial);
    finalize_kernel<<<1, 128, 0, stream>>>(partial, protos, q0, q1, out);
}